// Round 1
// baseline (1165.052 us; speedup 1.0000x reference)
//
#include <hip/hip_runtime.h>
#include <hip/hip_bf16.h>
#include <cstdint>

#define N_NODES 51200
#define N_GRAPH 256
#define NPG     200
#define N_EDGE  409600
#define EPG     1600
#define F_IN    768
#define HID     128
#define HEADS   4
#define HC      512   // HEADS*HID

// ---------------- workspace layout (bytes) ----------------
constexpr size_t SZ_A       = (size_t)N_NODES * HC * 4;           // 104857600
constexpr size_t OFF_A      = 0;                                  // H1raw; later h2raw/h2
constexpr size_t OFF_H1     = OFF_A + SZ_A;                       // h1 [N,512]
constexpr size_t OFF_ASRC1  = OFF_H1 + SZ_A;
constexpr size_t OFF_ADST1  = OFF_ASRC1 + (size_t)N_NODES * HEADS * 4;
constexpr size_t OFF_ASRC2  = OFF_ADST1 + (size_t)N_NODES * HEADS * 4;
constexpr size_t OFF_ADST2  = OFF_ASRC2 + (size_t)N_NODES * 4;
constexpr size_t OFF_S      = OFF_ADST2 + (size_t)N_NODES * 4;
constexpr size_t OFF_AGG    = OFF_S + (size_t)N_NODES * 2 * 4;
constexpr size_t OFF_SUB    = OFF_AGG + (size_t)N_GRAPH * 4 * 4;
constexpr size_t OFF_DEG    = OFF_SUB + (size_t)N_GRAPH * HID * 4;
constexpr size_t OFF_PART   = OFF_DEG + (size_t)N_NODES * 4;
constexpr size_t OFF_CNT    = OFF_PART + (size_t)N_NODES * 4;
constexpr size_t OFF_ROWPTR = OFF_CNT + (size_t)N_NODES * 4;
constexpr size_t OFF_ELIST  = OFF_ROWPTR + (size_t)(N_NODES + 1) * 4;
constexpr size_t OFF_BSUMS  = OFF_ELIST + (size_t)N_EDGE * 4;
constexpr size_t OFF_BOFFS  = OFF_BSUMS + 256 * 4;

__device__ __forceinline__ float leaky(float x) { return x >= 0.0f ? x : 0.2f * x; }

// ---------------- fp32 GEMM: C[M,Nn] = A[M,K] @ B[K,Nn] ----------------
// tile 128x64, 256 threads, 8x4 microtile, K-chunks of 16
__global__ __launch_bounds__(256)
void gemm_f32_kernel(const float* __restrict__ A, const float* __restrict__ B,
                     float* __restrict__ C, int M, int Nn, int K)
{
    __shared__ float As[16][132];
    __shared__ float Bs[16][68];
    const int tid = threadIdx.x;
    const int tx = tid & 15;   // col group (4 cols)
    const int ty = tid >> 4;   // row group (8 rows)
    const int m0 = blockIdx.x * 128;
    const int n0 = blockIdx.y * 64;
    const int ar = tid >> 2;   // 0..63
    const int aq = tid & 3;    // 0..3
    const int bk = tid >> 4;   // 0..15
    const int bq = tid & 15;   // 0..15
    float acc[8][4];
#pragma unroll
    for (int i = 0; i < 8; ++i)
#pragma unroll
        for (int j = 0; j < 4; ++j) acc[i][j] = 0.0f;

    const float* Aptr0 = A + (size_t)(m0 + ar) * K + aq * 4;
    const float* Aptr1 = A + (size_t)(m0 + ar + 64) * K + aq * 4;
    const float* Bptr  = B + (size_t)bk * Nn + n0 + bq * 4;

    for (int k0 = 0; k0 < K; k0 += 16) {
        float4 a0 = *(const float4*)(Aptr0 + k0);
        float4 a1 = *(const float4*)(Aptr1 + k0);
        float4 b0 = *(const float4*)(Bptr + (size_t)k0 * Nn);
        __syncthreads();
        As[aq*4+0][ar] = a0.x; As[aq*4+1][ar] = a0.y; As[aq*4+2][ar] = a0.z; As[aq*4+3][ar] = a0.w;
        As[aq*4+0][ar+64] = a1.x; As[aq*4+1][ar+64] = a1.y; As[aq*4+2][ar+64] = a1.z; As[aq*4+3][ar+64] = a1.w;
        *(float4*)&Bs[bk][bq*4] = b0;
        __syncthreads();
#pragma unroll
        for (int k = 0; k < 16; ++k) {
            float4 av0 = *(const float4*)&As[k][ty*8];
            float4 av1 = *(const float4*)&As[k][ty*8+4];
            float4 bv  = *(const float4*)&Bs[k][tx*4];
            float a8[8] = {av0.x, av0.y, av0.z, av0.w, av1.x, av1.y, av1.z, av1.w};
            float b4[4] = {bv.x, bv.y, bv.z, bv.w};
#pragma unroll
            for (int i = 0; i < 8; ++i)
#pragma unroll
                for (int j = 0; j < 4; ++j) acc[i][j] += a8[i] * b4[j];
        }
    }
#pragma unroll
    for (int i = 0; i < 8; ++i) {
        float4 v = make_float4(acc[i][0], acc[i][1], acc[i][2], acc[i][3]);
        *(float4*)&C[(size_t)(m0 + ty*8 + i) * Nn + n0 + tx*4] = v;
    }
}

// ---------------- per-node attention dots, layer 1 (4 heads) ----------------
// 4 nodes per block (one wave each)
__global__ __launch_bounds__(256)
void attn1_kernel(const float* __restrict__ H, const float* __restrict__ a_s,
                  const float* __restrict__ a_d, float* __restrict__ asrc,
                  float* __restrict__ adst)
{
    const int n = blockIdx.x * 4 + (threadIdx.x >> 6);
    const int l = threadIdx.x & 63;
    float ss[4], sd[4];
#pragma unroll
    for (int h = 0; h < 4; ++h) {
        const float* hp = H + (size_t)n * HC + h * HID;
        float v0 = hp[l], v1 = hp[l + 64];
        ss[h] = v0 * a_s[h*HID + l] + v1 * a_s[h*HID + 64 + l];
        sd[h] = v0 * a_d[h*HID + l] + v1 * a_d[h*HID + 64 + l];
    }
#pragma unroll
    for (int h = 0; h < 4; ++h) {
        for (int off = 32; off > 0; off >>= 1) {
            ss[h] += __shfl_down(ss[h], off);
            sd[h] += __shfl_down(sd[h], off);
        }
    }
    if (l == 0) {
#pragma unroll
        for (int h = 0; h < 4; ++h) {
            asrc[n*4 + h] = ss[h];
            adst[n*4 + h] = sd[h];
        }
    }
}

// ---------------- per-node attention dots, layer 2 (1 head) ----------------
__global__ __launch_bounds__(256)
void attn2_kernel(const float* __restrict__ H, const float* __restrict__ a_s,
                  const float* __restrict__ a_d, float* __restrict__ asrc,
                  float* __restrict__ adst)
{
    const int n = blockIdx.x * 4 + (threadIdx.x >> 6);
    const int l = threadIdx.x & 63;
    const float* hp = H + (size_t)n * HID;
    float v0 = hp[l], v1 = hp[l + 64];
    float ss = v0 * a_s[l] + v1 * a_s[64 + l];
    float sd = v0 * a_d[l] + v1 * a_d[64 + l];
    for (int off = 32; off > 0; off >>= 1) {
        ss += __shfl_down(ss, off);
        sd += __shfl_down(sd, off);
    }
    if (l == 0) { asrc[n] = ss; adst[n] = sd; }
}

// ---------------- CSR build ----------------
__global__ __launch_bounds__(256)
void hist_kernel(const int* __restrict__ dst0, int* __restrict__ deg)
{
    int e = blockIdx.x * 256 + threadIdx.x;
    atomicAdd(&deg[dst0[e]], 1);
}

__global__ __launch_bounds__(256)
void scan1_kernel(const int* __restrict__ deg, int* __restrict__ partial,
                  int* __restrict__ bsums)
{
    __shared__ int tmp[256];
    int t = threadIdx.x;
    int i = blockIdx.x * 256 + t;
    tmp[t] = deg[i];
    __syncthreads();
    for (int off = 1; off < 256; off <<= 1) {
        int v = (t >= off) ? tmp[t - off] : 0;
        __syncthreads();
        tmp[t] += v;
        __syncthreads();
    }
    partial[i] = tmp[t];
    if (t == 255) bsums[blockIdx.x] = tmp[255];
}

__global__ __launch_bounds__(256)
void scan2_kernel(const int* __restrict__ bsums, int* __restrict__ boffs, int nb)
{
    __shared__ int tmp[256];
    int t = threadIdx.x;
    tmp[t] = (t < nb) ? bsums[t] : 0;
    __syncthreads();
    for (int off = 1; off < 256; off <<= 1) {
        int v = (t >= off) ? tmp[t - off] : 0;
        __syncthreads();
        tmp[t] += v;
        __syncthreads();
    }
    if (t < nb) boffs[t] = (t == 0) ? 0 : tmp[t - 1];
}

__global__ __launch_bounds__(256)
void scan3_kernel(const int* __restrict__ partial, const int* __restrict__ boffs,
                  int* __restrict__ rowptr)
{
    int t = threadIdx.x;
    int i = blockIdx.x * 256 + t;
    rowptr[i + 1] = partial[i] + boffs[blockIdx.x];
    if (i == 0) rowptr[0] = 0;
}

__global__ __launch_bounds__(256)
void fill_kernel(const int* __restrict__ src0, const int* __restrict__ dst0,
                 const int* __restrict__ rowptr, int* __restrict__ cnt,
                 int* __restrict__ elist)
{
    int e = blockIdx.x * 256 + threadIdx.x;
    int d = dst0[e];
    int p = atomicAdd(&cnt[d], 1);
    elist[rowptr[d] + p] = src0[e];
}

// ---------------- GAT layer 1 aggregation (4 heads, 128 feat each) ----------------
// one block (256 threads) per dst node; self-loop handled analytically
__global__ __launch_bounds__(256)
void gat1_kernel(const float* __restrict__ H, const float* __restrict__ asrc,
                 const float* __restrict__ adst, const int* __restrict__ rowptr,
                 const int* __restrict__ elist, const float* __restrict__ b1,
                 float* __restrict__ out)
{
    const int n = blockIdx.x;
    const int tid = threadIdx.x;
    __shared__ int   s_src[64];
    __shared__ float s_w[4][64];
    __shared__ float s_adn[4], s_selfl[4], s_m[4], s_s[4];
    const int r0 = rowptr[n];
    const int deg = rowptr[n + 1] - r0;
    if (tid < 4) {
        float as_ = asrc[n*4 + tid];
        float ad_ = adst[n*4 + tid];
        s_adn[tid] = ad_;
        float l = leaky(as_ + ad_);
        s_selfl[tid] = l;
        s_m[tid] = l;
    }
    __syncthreads();
    // pass 1: segment max (self-loop already in s_m)
    for (int base = 0; base < deg; base += 64) {
        int len = min(64, deg - base);
        if (tid < len) s_src[tid] = elist[r0 + base + tid];
        __syncthreads();
        if (tid < 4) {
            float m = s_m[tid];
            float ad_ = s_adn[tid];
            for (int i = 0; i < len; ++i) {
                float l = leaky(asrc[s_src[i]*4 + tid] + ad_);
                m = fmaxf(m, l);
            }
            s_m[tid] = m;
        }
        __syncthreads();
    }
    const int c  = tid & 127;
    const int h0 = tid >> 7;   // 0 or 1
    const int h1 = h0 + 2;
    const float m_h0 = s_m[h0], m_h1 = s_m[h1];
    float acc0 = expf(s_selfl[h0] - m_h0) * H[(size_t)n*HC + h0*HID + c];
    float acc1 = expf(s_selfl[h1] - m_h1) * H[(size_t)n*HC + h1*HID + c];
    float rs = (tid < 4) ? expf(s_selfl[tid] - s_m[tid]) : 0.0f;
    // pass 2: weights + weighted accumulate
    for (int base = 0; base < deg; base += 64) {
        int len = min(64, deg - base);
        if (tid < len) s_src[tid] = elist[r0 + base + tid];
        __syncthreads();
        if (tid < 4 * len) {
            int i = tid >> 2, hh = tid & 3;
            float l = leaky(asrc[s_src[i]*4 + hh] + s_adn[hh]);
            s_w[hh][i] = expf(l - s_m[hh]);
        }
        __syncthreads();
        if (tid < 4) {
            for (int i = 0; i < len; ++i) rs += s_w[tid][i];
        }
        for (int i = 0; i < len; ++i) {
            int sidx = s_src[i];
            acc0 += s_w[h0][i] * H[(size_t)sidx*HC + h0*HID + c];
            acc1 += s_w[h1][i] * H[(size_t)sidx*HC + h1*HID + c];
        }
        __syncthreads();
    }
    if (tid < 4) s_s[tid] = rs;
    __syncthreads();
    float o0 = acc0 / (s_s[h0] + 1e-16f) + b1[h0*HID + c];
    float o1 = acc1 / (s_s[h1] + 1e-16f) + b1[h1*HID + c];
    out[(size_t)n*HC + h0*HID + c] = fmaxf(o0, 0.0f);
    out[(size_t)n*HC + h1*HID + c] = fmaxf(o1, 0.0f);
}

// ---------------- GAT layer 2 aggregation + cluster softmax S ----------------
__global__ __launch_bounds__(128)
void gat2_kernel(const float* __restrict__ H, const float* __restrict__ asrc,
                 const float* __restrict__ adst, const int* __restrict__ rowptr,
                 const int* __restrict__ elist, const float* __restrict__ b2,
                 const float* __restrict__ Wc, const float* __restrict__ bc,
                 float* __restrict__ h2, float* __restrict__ S)
{
    const int n = blockIdx.x;
    const int tid = threadIdx.x;
    __shared__ int   s_src[64];
    __shared__ float s_w[64];
    __shared__ float s_m, s_s, s_z0;
    __shared__ float s_red[128];
    const int r0 = rowptr[n];
    const int deg = rowptr[n + 1] - r0;
    const float adn = adst[n];
    const float selfl = leaky(asrc[n] + adn);
    if (tid == 0) s_m = selfl;
    __syncthreads();
    for (int base = 0; base < deg; base += 64) {
        int len = min(64, deg - base);
        if (tid < len) s_src[tid] = elist[r0 + base + tid];
        __syncthreads();
        if (tid == 0) {
            float m = s_m;
            for (int i = 0; i < len; ++i)
                m = fmaxf(m, leaky(asrc[s_src[i]] + adn));
            s_m = m;
        }
        __syncthreads();
    }
    const float mv = s_m;
    const float wself = expf(selfl - mv);
    float acc = wself * H[(size_t)n*HID + tid];
    float rs = wself;
    for (int base = 0; base < deg; base += 64) {
        int len = min(64, deg - base);
        if (tid < len) s_src[tid] = elist[r0 + base + tid];
        __syncthreads();
        if (tid < len) {
            float l = leaky(asrc[s_src[tid]] + adn);
            s_w[tid] = expf(l - mv);
        }
        __syncthreads();
        if (tid == 0) {
            for (int i = 0; i < len; ++i) rs += s_w[i];
        }
        for (int i = 0; i < len; ++i)
            acc += s_w[i] * H[(size_t)s_src[i]*HID + tid];
        __syncthreads();
    }
    if (tid == 0) s_s = rs;
    __syncthreads();
    float o = acc / (s_s + 1e-16f) + b2[tid];
    o = fmaxf(o, 0.0f);
    h2[(size_t)n*HID + tid] = o;
    // S = softmax([o . Wc[:,0], o . Wc[:,1]] + bc)
    s_red[tid] = o * Wc[tid*2 + 0];
    __syncthreads();
    for (int off = 64; off > 0; off >>= 1) {
        if (tid < off) s_red[tid] += s_red[tid + off];
        __syncthreads();
    }
    if (tid == 0) s_z0 = s_red[0] + bc[0];
    __syncthreads();
    s_red[tid] = o * Wc[tid*2 + 1];
    __syncthreads();
    for (int off = 64; off > 0; off >>= 1) {
        if (tid < off) s_red[tid] += s_red[tid + off];
        __syncthreads();
    }
    if (tid == 0) {
        float z0 = s_z0, z1 = s_red[0] + bc[1];
        float mm = fmaxf(z0, z1);
        float e0 = expf(z0 - mm), e1 = expf(z1 - mm);
        float inv = 1.0f / (e0 + e1);
        S[n*2 + 0] = e0 * inv;
        S[n*2 + 1] = e1 * inv;
    }
}

// ---------------- per-graph S^T A S (2x2) ----------------
__global__ __launch_bounds__(256)
void agg_kernel(const int* __restrict__ src0, const int* __restrict__ dst0,
                const float* __restrict__ S, float* __restrict__ agg)
{
    const int g = blockIdx.x, tid = threadIdx.x;
    float a00 = 0, a01 = 0, a10 = 0, a11 = 0;
    for (int e = g*EPG + tid; e < (g + 1)*EPG; e += 256) {
        int s = src0[e], d = dst0[e];
        float s0 = S[s*2], s1 = S[s*2 + 1];
        float d0 = S[d*2], d1 = S[d*2 + 1];
        a00 += s0*d0; a01 += s0*d1; a10 += s1*d0; a11 += s1*d1;
    }
    for (int off = 32; off > 0; off >>= 1) {
        a00 += __shfl_down(a00, off); a01 += __shfl_down(a01, off);
        a10 += __shfl_down(a10, off); a11 += __shfl_down(a11, off);
    }
    __shared__ float sred[4][4];
    if ((tid & 63) == 0) {
        int w = tid >> 6;
        sred[w][0] = a00; sred[w][1] = a01; sred[w][2] = a10; sred[w][3] = a11;
    }
    __syncthreads();
    if (tid == 0) {
        agg[g*4 + 0] = sred[0][0] + sred[1][0] + sred[2][0] + sred[3][0];
        agg[g*4 + 1] = sred[0][1] + sred[1][1] + sred[2][1] + sred[3][1];
        agg[g*4 + 2] = sred[0][2] + sred[1][2] + sred[2][2] + sred[3][2];
        agg[g*4 + 3] = sred[0][3] + sred[1][3] + sred[2][3] + sred[3][3];
    }
}

__global__ __launch_bounds__(256)
void loss_kernel(const float* __restrict__ agg, float* __restrict__ out_loss)
{
    int tid = threadIdx.x;   // == graph id, G == 256
    float a00 = agg[tid*4 + 0], a01 = agg[tid*4 + 1];
    float a10 = agg[tid*4 + 2], a11 = agg[tid*4 + 3];
    float rn0 = fmaxf(fabsf(a00) + fabsf(a01), 1e-5f);
    float rn1 = fmaxf(fabsf(a10) + fabsf(a11), 1e-5f);
    float d0 = a00 / rn0 - 1.0f, d1 = a11 / rn1 - 1.0f;
    float contrib = 0.5f * (d0*d0 + d1*d1);
    for (int off = 32; off > 0; off >>= 1) contrib += __shfl_down(contrib, off);
    __shared__ float sred[4];
    if ((tid & 63) == 0) sred[tid >> 6] = contrib;
    __syncthreads();
    if (tid == 0)
        out_loss[0] = (sred[0] + sred[1] + sred[2] + sred[3]) * (1.0f / N_GRAPH);
}

// ---------------- per-graph pooled embedding ----------------
__global__ __launch_bounds__(128)
void sub_kernel(const float* __restrict__ S, const float* __restrict__ h2,
                float* __restrict__ sub)
{
    const int g = blockIdx.x, c = threadIdx.x;
    const float* Sg = S + (size_t)g * NPG * 2;
    const float* hg = h2 + (size_t)g * NPG * HID;
    float acc = 0.0f;
    for (int i = 0; i < NPG; ++i)
        acc += Sg[i*2] * hg[(size_t)i*HID + c];
    sub[g*HID + c] = acc;
}

// ---------------- final MLP head ----------------
__global__ __launch_bounds__(128)
void final_kernel(const float* __restrict__ sub, const float* __restrict__ Wf1,
                  const float* __restrict__ bf1, const float* __restrict__ Wf2,
                  const float* __restrict__ bf2, float* __restrict__ out)
{
    __shared__ float s_sub[128];
    __shared__ float s_fc[128];
    const int g = blockIdx.x, t = threadIdx.x;
    s_sub[t] = sub[g*HID + t];
    __syncthreads();
    float acc = bf1[t];
    for (int c = 0; c < 128; ++c)
        acc += s_sub[c] * Wf1[c*128 + t];
    s_fc[t] = fmaxf(acc, 0.0f);
    __syncthreads();
    if (t < 2) {
        float z = bf2[t];
        for (int j = 0; j < 128; ++j) z += s_fc[j] * Wf2[j*2 + t];
        out[g*2 + t] = z;
    }
}

extern "C" void kernel_launch(void* const* d_in, const int* in_sizes, int n_in,
                              void* d_out, int out_size, void* d_ws, size_t ws_size,
                              hipStream_t stream)
{
    const float* x   = (const float*)d_in[0];
    const int*   ei  = (const int*)d_in[1];
    const float* W1  = (const float*)d_in[3];
    const float* as1 = (const float*)d_in[4];
    const float* ad1 = (const float*)d_in[5];
    const float* b1  = (const float*)d_in[6];
    const float* W2  = (const float*)d_in[7];
    const float* as2 = (const float*)d_in[8];
    const float* ad2 = (const float*)d_in[9];
    const float* b2  = (const float*)d_in[10];
    const float* Wc  = (const float*)d_in[11];
    const float* bc  = (const float*)d_in[12];
    const float* Wf1 = (const float*)d_in[13];
    const float* bf1 = (const float*)d_in[14];
    const float* Wf2 = (const float*)d_in[15];
    const float* bf2 = (const float*)d_in[16];
    const int* src0 = ei;
    const int* dst0 = ei + N_EDGE;

    char* ws = (char*)d_ws;
    float* H1raw = (float*)(ws + OFF_A);
    float* h1    = (float*)(ws + OFF_H1);
    float* h2raw = (float*)(ws + OFF_A);                                  // overlay (H1raw dead)
    float* h2    = (float*)(ws + OFF_A + (size_t)N_NODES * HID * 4);      // overlay
    float* asrc1 = (float*)(ws + OFF_ASRC1);
    float* adst1 = (float*)(ws + OFF_ADST1);
    float* asrc2 = (float*)(ws + OFF_ASRC2);
    float* adst2 = (float*)(ws + OFF_ADST2);
    float* Sbuf  = (float*)(ws + OFF_S);
    float* aggb  = (float*)(ws + OFF_AGG);
    float* subb  = (float*)(ws + OFF_SUB);
    int* deg     = (int*)(ws + OFF_DEG);
    int* part    = (int*)(ws + OFF_PART);
    int* cnt     = (int*)(ws + OFF_CNT);
    int* rowptr  = (int*)(ws + OFF_ROWPTR);
    int* elist   = (int*)(ws + OFF_ELIST);
    int* bsums   = (int*)(ws + OFF_BSUMS);
    int* boffs   = (int*)(ws + OFF_BOFFS);
    float* out   = (float*)d_out;

    hipMemsetAsync(deg, 0, (size_t)N_NODES * 4, stream);
    hipMemsetAsync(cnt, 0, (size_t)N_NODES * 4, stream);

    // GEMM1: H1raw = x @ W1
    gemm_f32_kernel<<<dim3(N_NODES/128, HC/64), 256, 0, stream>>>(x, W1, H1raw, N_NODES, HC, F_IN);
    attn1_kernel<<<N_NODES/4, 256, 0, stream>>>(H1raw, as1, ad1, asrc1, adst1);

    // CSR (dst-grouped) of original edges
    hist_kernel<<<N_EDGE/256, 256, 0, stream>>>(dst0, deg);
    scan1_kernel<<<N_NODES/256, 256, 0, stream>>>(deg, part, bsums);
    scan2_kernel<<<1, 256, 0, stream>>>(bsums, boffs, N_NODES/256);
    scan3_kernel<<<N_NODES/256, 256, 0, stream>>>(part, boffs, rowptr);
    fill_kernel<<<N_EDGE/256, 256, 0, stream>>>(src0, dst0, rowptr, cnt, elist);

    gat1_kernel<<<N_NODES, 256, 0, stream>>>(H1raw, asrc1, adst1, rowptr, elist, b1, h1);

    // GEMM2: h2raw = h1 @ W2
    gemm_f32_kernel<<<dim3(N_NODES/128, HID/64), 256, 0, stream>>>(h1, W2, h2raw, N_NODES, HID, HC);
    attn2_kernel<<<N_NODES/4, 256, 0, stream>>>(h2raw, as2, ad2, asrc2, adst2);

    gat2_kernel<<<N_NODES, 128, 0, stream>>>(h2raw, asrc2, adst2, rowptr, elist, b2, Wc, bc, h2, Sbuf);

    agg_kernel<<<N_GRAPH, 256, 0, stream>>>(src0, dst0, Sbuf, aggb);
    loss_kernel<<<1, 256, 0, stream>>>(aggb, out + N_GRAPH*2);

    sub_kernel<<<N_GRAPH, 128, 0, stream>>>(Sbuf, h2, subb);
    final_kernel<<<N_GRAPH, 128, 0, stream>>>(subb, Wf1, bf1, Wf2, bf2, out);

    (void)in_sizes; (void)n_in; (void)out_size; (void)ws_size;
}

// Round 2
// 722.271 us; speedup vs baseline: 1.6130x; 1.6130x over previous
//
#include <hip/hip_runtime.h>
#include <hip/hip_bf16.h>
#include <cstdint>

#define N_NODES 51200
#define N_GRAPH 256
#define NPG     200
#define N_EDGE  409600
#define EPG     1600
#define F_IN    768
#define HID     128
#define HEADS   4
#define HC      512   // HEADS*HID

typedef __attribute__((ext_vector_type(8))) short short8;
typedef __attribute__((ext_vector_type(4))) float floatx4;

// ---------------- workspace layout (bytes) ----------------
constexpr size_t SZ_H1RAW   = (size_t)N_NODES * HC * 4;            // 104857600
constexpr size_t OFF_A      = 0;                                   // H1raw fp32; later h2raw+h2 overlay
constexpr size_t OFF_H1B    = OFF_A + SZ_H1RAW;                    // h1 bf16 [N,512]
constexpr size_t OFF_WT1    = OFF_H1B + (size_t)N_NODES * HC * 2;  // Wt1 bf16 [512][768]
constexpr size_t OFF_WT2    = OFF_WT1 + (size_t)HC * F_IN * 2;     // Wt2 bf16 [128][512]
constexpr size_t OFF_ASRC1  = OFF_WT2 + (size_t)HID * HC * 2;
constexpr size_t OFF_ADST1  = OFF_ASRC1 + (size_t)N_NODES * HEADS * 4;
constexpr size_t OFF_ASRC2  = OFF_ADST1 + (size_t)N_NODES * HEADS * 4;
constexpr size_t OFF_ADST2  = OFF_ASRC2 + (size_t)N_NODES * 4;
constexpr size_t OFF_S      = OFF_ADST2 + (size_t)N_NODES * 4;
constexpr size_t OFF_AGG    = OFF_S + (size_t)N_NODES * 2 * 4;
constexpr size_t OFF_SUB    = OFF_AGG + (size_t)N_GRAPH * 4 * 4;
constexpr size_t OFF_DEG    = OFF_SUB + (size_t)N_GRAPH * HID * 4;
constexpr size_t OFF_PART   = OFF_DEG + (size_t)N_NODES * 4;
constexpr size_t OFF_CNT    = OFF_PART + (size_t)N_NODES * 4;
constexpr size_t OFF_ROWPTR = OFF_CNT + (size_t)N_NODES * 4;
constexpr size_t OFF_ELIST  = OFF_ROWPTR + (size_t)(N_NODES + 1) * 4;
constexpr size_t OFF_BSUMS  = OFF_ELIST + (size_t)N_EDGE * 4;
constexpr size_t OFF_BOFFS  = OFF_BSUMS + 256 * 4;

__device__ __forceinline__ float leaky(float x) { return x >= 0.0f ? x : 0.2f * x; }

__device__ __forceinline__ unsigned short f2bf(float f) {
    unsigned int u = __float_as_uint(f);
    u += 0x7fffu + ((u >> 16) & 1u);            // RNE
    return (unsigned short)(u >> 16);
}

__device__ __forceinline__ void gl_lds16(const void* g, void* l) {
    __builtin_amdgcn_global_load_lds(
        (__attribute__((address_space(1))) void*)(g),
        (__attribute__((address_space(3))) void*)(l),
        16, 0, 0);
}

// ---------------- W [K][N] fp32 -> Wt [N][K] bf16 ----------------
__global__ __launch_bounds__(256)
void transpose_cvt_kernel(const float* __restrict__ W, short* __restrict__ Wt,
                          int K, int Nn)
{
    int idx = blockIdx.x * 256 + threadIdx.x;
    if (idx >= K * Nn) return;
    int k = idx / Nn, n = idx % Nn;             // coalesced read
    Wt[(size_t)n * K + k] = (short)f2bf(W[idx]);
}

// ---------------- MFMA bf16 GEMM: C[M,Nn] = A[M,K] @ Bt[Nn,K]^T ----------------
// 128x128 tile, BK=32, 256 threads (4 waves, 2x2), each wave 4x4 of 16x16x32.
// LDS fragment-blob layout: [tile16 (8)][kgrp (4)][mm (16)][kk (8)] bf16 so each
// ds_read_b128 is lane-contiguous (conflict-free) and matches global_load_lds's
// base + lane*16 write pattern.
template <bool A_BF16>
__global__ __launch_bounds__(256)
void gemm_mfma_kernel(const void* __restrict__ Av, const short* __restrict__ Bt,
                      float* __restrict__ C, int M, int Nn, int K)
{
    __shared__ __align__(16) short Ablob[4096];   // 8 KB
    __shared__ __align__(16) short Bblob[4096];   // 8 KB
    const int tid = threadIdx.x;
    const int w = tid >> 6, l = tid & 63;
    const int m0 = blockIdx.x * 128, n0 = blockIdx.y * 128;
    const int wr = w >> 1, wc = w & 1;

    floatx4 acc[4][4];
#pragma unroll
    for (int i = 0; i < 4; ++i)
#pragma unroll
        for (int j = 0; j < 4; ++j) acc[i][j] = (floatx4)0.0f;

    // B staging: wave w issues fragment-blocks {2w, 2w+1} via global_load_lds
    const short* bgp = Bt + (size_t)(n0 + (w * 2) * 16 + (l & 15)) * K + ((l >> 4) * 8);

    // A staging setup
    const float* Af = (const float*)Av;
    const short* Ab = (const short*)Av;
    const int r = tid >> 1, hh = tid & 1;                   // fp32 path
    const float* arow = Af + (size_t)(m0 + r) * K + hh * 16;
    const short* agp = Ab + (size_t)(m0 + (w * 2) * 16 + (l & 15)) * K + ((l >> 4) * 8);

    float4 pf0, pf1, pf2, pf3;
    if constexpr (!A_BF16) {
        pf0 = *(const float4*)(arow + 0);
        pf1 = *(const float4*)(arow + 4);
        pf2 = *(const float4*)(arow + 8);
        pf3 = *(const float4*)(arow + 12);
    }

    for (int k0 = 0; k0 < K; k0 += 32) {
        __syncthreads();   // previous compute done reading LDS; drains prefetch loads
        if constexpr (A_BF16) {
            gl_lds16(agp + k0,          &Ablob[(w * 2) * 512]);
            gl_lds16(agp + 16 * K + k0, &Ablob[(w * 2 + 1) * 512]);
        } else {
            unsigned short us[16];
            us[0]=f2bf(pf0.x); us[1]=f2bf(pf0.y); us[2]=f2bf(pf0.z); us[3]=f2bf(pf0.w);
            us[4]=f2bf(pf1.x); us[5]=f2bf(pf1.y); us[6]=f2bf(pf1.z); us[7]=f2bf(pf1.w);
            us[8]=f2bf(pf2.x); us[9]=f2bf(pf2.y); us[10]=f2bf(pf2.z); us[11]=f2bf(pf2.w);
            us[12]=f2bf(pf3.x); us[13]=f2bf(pf3.y); us[14]=f2bf(pf3.z); us[15]=f2bf(pf3.w);
            const int o = (r >> 4) * 512 + (2 * hh) * 128 + (r & 15) * 8;
            short8 v0, v1;
#pragma unroll
            for (int j = 0; j < 8; ++j) { v0[j] = (short)us[j]; v1[j] = (short)us[8 + j]; }
            *(short8*)&Ablob[o]       = v0;
            *(short8*)&Ablob[o + 128] = v1;
        }
        gl_lds16(bgp + k0,          &Bblob[(w * 2) * 512]);
        gl_lds16(bgp + 16 * K + k0, &Bblob[(w * 2 + 1) * 512]);
        __syncthreads();   // implies vmcnt(0): LDS fully staged

        if constexpr (!A_BF16) {
            if (k0 + 32 < K) {     // prefetch next chunk; overlaps MFMA below
                pf0 = *(const float4*)(arow + k0 + 32);
                pf1 = *(const float4*)(arow + k0 + 36);
                pf2 = *(const float4*)(arow + k0 + 40);
                pf3 = *(const float4*)(arow + k0 + 44);
            }
        }

        short8 af[4], bfr[4];
#pragma unroll
        for (int mi = 0; mi < 4; ++mi)
            af[mi] = *(const short8*)&Ablob[(wr * 4 + mi) * 512 + l * 8];
#pragma unroll
        for (int ni = 0; ni < 4; ++ni)
            bfr[ni] = *(const short8*)&Bblob[(wc * 4 + ni) * 512 + l * 8];
#pragma unroll
        for (int mi = 0; mi < 4; ++mi)
#pragma unroll
            for (int ni = 0; ni < 4; ++ni)
                acc[mi][ni] = __builtin_amdgcn_mfma_f32_16x16x32_bf16(
                    af[mi], bfr[ni], acc[mi][ni], 0, 0, 0);
    }

    const int lr = (l >> 4) * 4, lc = l & 15;   // C/D: col=lane&15, row=(lane>>4)*4+reg
#pragma unroll
    for (int mi = 0; mi < 4; ++mi)
#pragma unroll
        for (int ni = 0; ni < 4; ++ni) {
            const size_t base = (size_t)(m0 + wr * 64 + mi * 16 + lr) * Nn
                              + (n0 + wc * 64 + ni * 16 + lc);
#pragma unroll
            for (int rr = 0; rr < 4; ++rr)
                C[base + (size_t)rr * Nn] = acc[mi][ni][rr];
        }
}

// ---------------- per-node attention dots, layer 1 (4 heads) ----------------
__global__ __launch_bounds__(256)
void attn1_kernel(const float* __restrict__ H, const float* __restrict__ a_s,
                  const float* __restrict__ a_d, float* __restrict__ asrc,
                  float* __restrict__ adst)
{
    const int n = blockIdx.x * 4 + (threadIdx.x >> 6);
    const int l = threadIdx.x & 63;
    float ss[4], sd[4];
#pragma unroll
    for (int h = 0; h < 4; ++h) {
        const float* hp = H + (size_t)n * HC + h * HID;
        float v0 = hp[l], v1 = hp[l + 64];
        ss[h] = v0 * a_s[h*HID + l] + v1 * a_s[h*HID + 64 + l];
        sd[h] = v0 * a_d[h*HID + l] + v1 * a_d[h*HID + 64 + l];
    }
#pragma unroll
    for (int h = 0; h < 4; ++h) {
        for (int off = 32; off > 0; off >>= 1) {
            ss[h] += __shfl_down(ss[h], off);
            sd[h] += __shfl_down(sd[h], off);
        }
    }
    if (l == 0) {
#pragma unroll
        for (int h = 0; h < 4; ++h) {
            asrc[n*4 + h] = ss[h];
            adst[n*4 + h] = sd[h];
        }
    }
}

// ---------------- per-node attention dots, layer 2 (1 head) ----------------
__global__ __launch_bounds__(256)
void attn2_kernel(const float* __restrict__ H, const float* __restrict__ a_s,
                  const float* __restrict__ a_d, float* __restrict__ asrc,
                  float* __restrict__ adst)
{
    const int n = blockIdx.x * 4 + (threadIdx.x >> 6);
    const int l = threadIdx.x & 63;
    const float* hp = H + (size_t)n * HID;
    float v0 = hp[l], v1 = hp[l + 64];
    float ss = v0 * a_s[l] + v1 * a_s[64 + l];
    float sd = v0 * a_d[l] + v1 * a_d[64 + l];
    for (int off = 32; off > 0; off >>= 1) {
        ss += __shfl_down(ss, off);
        sd += __shfl_down(sd, off);
    }
    if (l == 0) { asrc[n] = ss; adst[n] = sd; }
}

// ---------------- CSR build ----------------
__global__ __launch_bounds__(256)
void hist_kernel(const int* __restrict__ dst0, int* __restrict__ deg)
{
    int e = blockIdx.x * 256 + threadIdx.x;
    atomicAdd(&deg[dst0[e]], 1);
}

__global__ __launch_bounds__(256)
void scan1_kernel(const int* __restrict__ deg, int* __restrict__ partial,
                  int* __restrict__ bsums)
{
    __shared__ int tmp[256];
    int t = threadIdx.x;
    int i = blockIdx.x * 256 + t;
    tmp[t] = deg[i];
    __syncthreads();
    for (int off = 1; off < 256; off <<= 1) {
        int v = (t >= off) ? tmp[t - off] : 0;
        __syncthreads();
        tmp[t] += v;
        __syncthreads();
    }
    partial[i] = tmp[t];
    if (t == 255) bsums[blockIdx.x] = tmp[255];
}

__global__ __launch_bounds__(256)
void scan2_kernel(const int* __restrict__ bsums, int* __restrict__ boffs, int nb)
{
    __shared__ int tmp[256];
    int t = threadIdx.x;
    tmp[t] = (t < nb) ? bsums[t] : 0;
    __syncthreads();
    for (int off = 1; off < 256; off <<= 1) {
        int v = (t >= off) ? tmp[t - off] : 0;
        __syncthreads();
        tmp[t] += v;
        __syncthreads();
    }
    if (t < nb) boffs[t] = (t == 0) ? 0 : tmp[t - 1];
}

__global__ __launch_bounds__(256)
void scan3_kernel(const int* __restrict__ partial, const int* __restrict__ boffs,
                  int* __restrict__ rowptr)
{
    int t = threadIdx.x;
    int i = blockIdx.x * 256 + t;
    rowptr[i + 1] = partial[i] + boffs[blockIdx.x];
    if (i == 0) rowptr[0] = 0;
}

__global__ __launch_bounds__(256)
void fill_kernel(const int* __restrict__ src0, const int* __restrict__ dst0,
                 const int* __restrict__ rowptr, int* __restrict__ cnt,
                 int* __restrict__ elist)
{
    int e = blockIdx.x * 256 + threadIdx.x;
    int d = dst0[e];
    int p = atomicAdd(&cnt[d], 1);
    elist[rowptr[d] + p] = src0[e];
}

// ---------------- GAT layer 1 aggregation (4 heads, 128 feat each) ----------------
// one block (256 threads) per dst node; self-loop handled analytically; h1 out bf16
__global__ __launch_bounds__(256)
void gat1_kernel(const float* __restrict__ H, const float* __restrict__ asrc,
                 const float* __restrict__ adst, const int* __restrict__ rowptr,
                 const int* __restrict__ elist, const float* __restrict__ b1,
                 short* __restrict__ out)
{
    const int n = blockIdx.x;
    const int tid = threadIdx.x;
    __shared__ int   s_src[64];
    __shared__ float s_w[4][64];
    __shared__ float s_adn[4], s_selfl[4], s_m[4], s_s[4];
    const int r0 = rowptr[n];
    const int deg = rowptr[n + 1] - r0;
    if (tid < 4) {
        float as_ = asrc[n*4 + tid];
        float ad_ = adst[n*4 + tid];
        s_adn[tid] = ad_;
        float l = leaky(as_ + ad_);
        s_selfl[tid] = l;
        s_m[tid] = l;
    }
    __syncthreads();
    for (int base = 0; base < deg; base += 64) {
        int len = min(64, deg - base);
        if (tid < len) s_src[tid] = elist[r0 + base + tid];
        __syncthreads();
        if (tid < 4) {
            float m = s_m[tid];
            float ad_ = s_adn[tid];
            for (int i = 0; i < len; ++i) {
                float l = leaky(asrc[s_src[i]*4 + tid] + ad_);
                m = fmaxf(m, l);
            }
            s_m[tid] = m;
        }
        __syncthreads();
    }
    const int c  = tid & 127;
    const int h0 = tid >> 7;   // 0 or 1
    const int h1 = h0 + 2;
    const float m_h0 = s_m[h0], m_h1 = s_m[h1];
    float acc0 = expf(s_selfl[h0] - m_h0) * H[(size_t)n*HC + h0*HID + c];
    float acc1 = expf(s_selfl[h1] - m_h1) * H[(size_t)n*HC + h1*HID + c];
    float rs = (tid < 4) ? expf(s_selfl[tid] - s_m[tid]) : 0.0f;
    for (int base = 0; base < deg; base += 64) {
        int len = min(64, deg - base);
        if (tid < len) s_src[tid] = elist[r0 + base + tid];
        __syncthreads();
        if (tid < 4 * len) {
            int i = tid >> 2, hhh = tid & 3;
            float l = leaky(asrc[s_src[i]*4 + hhh] + s_adn[hhh]);
            s_w[hhh][i] = expf(l - s_m[hhh]);
        }
        __syncthreads();
        if (tid < 4) {
            for (int i = 0; i < len; ++i) rs += s_w[tid][i];
        }
        for (int i = 0; i < len; ++i) {
            int sidx = s_src[i];
            acc0 += s_w[h0][i] * H[(size_t)sidx*HC + h0*HID + c];
            acc1 += s_w[h1][i] * H[(size_t)sidx*HC + h1*HID + c];
        }
        __syncthreads();
    }
    if (tid < 4) s_s[tid] = rs;
    __syncthreads();
    float o0 = acc0 / (s_s[h0] + 1e-16f) + b1[h0*HID + c];
    float o1 = acc1 / (s_s[h1] + 1e-16f) + b1[h1*HID + c];
    out[(size_t)n*HC + h0*HID + c] = (short)f2bf(fmaxf(o0, 0.0f));
    out[(size_t)n*HC + h1*HID + c] = (short)f2bf(fmaxf(o1, 0.0f));
}

// ---------------- GAT layer 2 aggregation + cluster softmax S ----------------
__global__ __launch_bounds__(128)
void gat2_kernel(const float* __restrict__ H, const float* __restrict__ asrc,
                 const float* __restrict__ adst, const int* __restrict__ rowptr,
                 const int* __restrict__ elist, const float* __restrict__ b2,
                 const float* __restrict__ Wc, const float* __restrict__ bc,
                 float* __restrict__ h2, float* __restrict__ S)
{
    const int n = blockIdx.x;
    const int tid = threadIdx.x;
    __shared__ int   s_src[64];
    __shared__ float s_w[64];
    __shared__ float s_m, s_s, s_z0;
    __shared__ float s_red[128];
    const int r0 = rowptr[n];
    const int deg = rowptr[n + 1] - r0;
    const float adn = adst[n];
    const float selfl = leaky(asrc[n] + adn);
    if (tid == 0) s_m = selfl;
    __syncthreads();
    for (int base = 0; base < deg; base += 64) {
        int len = min(64, deg - base);
        if (tid < len) s_src[tid] = elist[r0 + base + tid];
        __syncthreads();
        if (tid == 0) {
            float m = s_m;
            for (int i = 0; i < len; ++i)
                m = fmaxf(m, leaky(asrc[s_src[i]] + adn));
            s_m = m;
        }
        __syncthreads();
    }
    const float mv = s_m;
    const float wself = expf(selfl - mv);
    float acc = wself * H[(size_t)n*HID + tid];
    float rs = wself;
    for (int base = 0; base < deg; base += 64) {
        int len = min(64, deg - base);
        if (tid < len) s_src[tid] = elist[r0 + base + tid];
        __syncthreads();
        if (tid < len) {
            float l = leaky(asrc[s_src[tid]] + adn);
            s_w[tid] = expf(l - mv);
        }
        __syncthreads();
        if (tid == 0) {
            for (int i = 0; i < len; ++i) rs += s_w[i];
        }
        for (int i = 0; i < len; ++i)
            acc += s_w[i] * H[(size_t)s_src[i]*HID + tid];
        __syncthreads();
    }
    if (tid == 0) s_s = rs;
    __syncthreads();
    float o = acc / (s_s + 1e-16f) + b2[tid];
    o = fmaxf(o, 0.0f);
    h2[(size_t)n*HID + tid] = o;
    s_red[tid] = o * Wc[tid*2 + 0];
    __syncthreads();
    for (int off = 64; off > 0; off >>= 1) {
        if (tid < off) s_red[tid] += s_red[tid + off];
        __syncthreads();
    }
    if (tid == 0) s_z0 = s_red[0] + bc[0];
    __syncthreads();
    s_red[tid] = o * Wc[tid*2 + 1];
    __syncthreads();
    for (int off = 64; off > 0; off >>= 1) {
        if (tid < off) s_red[tid] += s_red[tid + off];
        __syncthreads();
    }
    if (tid == 0) {
        float z0 = s_z0, z1 = s_red[0] + bc[1];
        float mm = fmaxf(z0, z1);
        float e0 = expf(z0 - mm), e1 = expf(z1 - mm);
        float inv = 1.0f / (e0 + e1);
        S[n*2 + 0] = e0 * inv;
        S[n*2 + 1] = e1 * inv;
    }
}

// ---------------- per-graph S^T A S (2x2) ----------------
__global__ __launch_bounds__(256)
void agg_kernel(const int* __restrict__ src0, const int* __restrict__ dst0,
                const float* __restrict__ S, float* __restrict__ agg)
{
    const int g = blockIdx.x, tid = threadIdx.x;
    float a00 = 0, a01 = 0, a10 = 0, a11 = 0;
    for (int e = g*EPG + tid; e < (g + 1)*EPG; e += 256) {
        int s = src0[e], d = dst0[e];
        float s0 = S[s*2], s1 = S[s*2 + 1];
        float d0 = S[d*2], d1 = S[d*2 + 1];
        a00 += s0*d0; a01 += s0*d1; a10 += s1*d0; a11 += s1*d1;
    }
    for (int off = 32; off > 0; off >>= 1) {
        a00 += __shfl_down(a00, off); a01 += __shfl_down(a01, off);
        a10 += __shfl_down(a10, off); a11 += __shfl_down(a11, off);
    }
    __shared__ float sred[4][4];
    if ((tid & 63) == 0) {
        int w = tid >> 6;
        sred[w][0] = a00; sred[w][1] = a01; sred[w][2] = a10; sred[w][3] = a11;
    }
    __syncthreads();
    if (tid == 0) {
        agg[g*4 + 0] = sred[0][0] + sred[1][0] + sred[2][0] + sred[3][0];
        agg[g*4 + 1] = sred[0][1] + sred[1][1] + sred[2][1] + sred[3][1];
        agg[g*4 + 2] = sred[0][2] + sred[1][2] + sred[2][2] + sred[3][2];
        agg[g*4 + 3] = sred[0][3] + sred[1][3] + sred[2][3] + sred[3][3];
    }
}

__global__ __launch_bounds__(256)
void loss_kernel(const float* __restrict__ agg, float* __restrict__ out_loss)
{
    int tid = threadIdx.x;   // == graph id, G == 256
    float a00 = agg[tid*4 + 0], a01 = agg[tid*4 + 1];
    float a10 = agg[tid*4 + 2], a11 = agg[tid*4 + 3];
    float rn0 = fmaxf(fabsf(a00) + fabsf(a01), 1e-5f);
    float rn1 = fmaxf(fabsf(a10) + fabsf(a11), 1e-5f);
    float d0 = a00 / rn0 - 1.0f, d1 = a11 / rn1 - 1.0f;
    float contrib = 0.5f * (d0*d0 + d1*d1);
    for (int off = 32; off > 0; off >>= 1) contrib += __shfl_down(contrib, off);
    __shared__ float sred[4];
    if ((tid & 63) == 0) sred[tid >> 6] = contrib;
    __syncthreads();
    if (tid == 0)
        out_loss[0] = (sred[0] + sred[1] + sred[2] + sred[3]) * (1.0f / N_GRAPH);
}

// ---------------- per-graph pooled embedding ----------------
__global__ __launch_bounds__(128)
void sub_kernel(const float* __restrict__ S, const float* __restrict__ h2,
                float* __restrict__ sub)
{
    const int g = blockIdx.x, c = threadIdx.x;
    const float* Sg = S + (size_t)g * NPG * 2;
    const float* hg = h2 + (size_t)g * NPG * HID;
    float acc = 0.0f;
    for (int i = 0; i < NPG; ++i)
        acc += Sg[i*2] * hg[(size_t)i*HID + c];
    sub[g*HID + c] = acc;
}

// ---------------- final MLP head ----------------
__global__ __launch_bounds__(128)
void final_kernel(const float* __restrict__ sub, const float* __restrict__ Wf1,
                  const float* __restrict__ bf1, const float* __restrict__ Wf2,
                  const float* __restrict__ bf2, float* __restrict__ out)
{
    __shared__ float s_sub[128];
    __shared__ float s_fc[128];
    const int g = blockIdx.x, t = threadIdx.x;
    s_sub[t] = sub[g*HID + t];
    __syncthreads();
    float acc = bf1[t];
    for (int c = 0; c < 128; ++c)
        acc += s_sub[c] * Wf1[c*128 + t];
    s_fc[t] = fmaxf(acc, 0.0f);
    __syncthreads();
    if (t < 2) {
        float z = bf2[t];
        for (int j = 0; j < 128; ++j) z += s_fc[j] * Wf2[j*2 + t];
        out[g*2 + t] = z;
    }
}

extern "C" void kernel_launch(void* const* d_in, const int* in_sizes, int n_in,
                              void* d_out, int out_size, void* d_ws, size_t ws_size,
                              hipStream_t stream)
{
    const float* x   = (const float*)d_in[0];
    const int*   ei  = (const int*)d_in[1];
    const float* W1  = (const float*)d_in[3];
    const float* as1 = (const float*)d_in[4];
    const float* ad1 = (const float*)d_in[5];
    const float* b1  = (const float*)d_in[6];
    const float* W2  = (const float*)d_in[7];
    const float* as2 = (const float*)d_in[8];
    const float* ad2 = (const float*)d_in[9];
    const float* b2  = (const float*)d_in[10];
    const float* Wc  = (const float*)d_in[11];
    const float* bc  = (const float*)d_in[12];
    const float* Wf1 = (const float*)d_in[13];
    const float* bf1 = (const float*)d_in[14];
    const float* Wf2 = (const float*)d_in[15];
    const float* bf2 = (const float*)d_in[16];
    const int* src0 = ei;
    const int* dst0 = ei + N_EDGE;

    char* ws = (char*)d_ws;
    float* H1raw = (float*)(ws + OFF_A);
    short* h1b   = (short*)(ws + OFF_H1B);
    short* Wt1   = (short*)(ws + OFF_WT1);
    short* Wt2   = (short*)(ws + OFF_WT2);
    float* h2raw = (float*)(ws + OFF_A);                                  // overlay (H1raw dead)
    float* h2    = (float*)(ws + OFF_A + (size_t)N_NODES * HID * 4);      // overlay
    float* asrc1 = (float*)(ws + OFF_ASRC1);
    float* adst1 = (float*)(ws + OFF_ADST1);
    float* asrc2 = (float*)(ws + OFF_ASRC2);
    float* adst2 = (float*)(ws + OFF_ADST2);
    float* Sbuf  = (float*)(ws + OFF_S);
    float* aggb  = (float*)(ws + OFF_AGG);
    float* subb  = (float*)(ws + OFF_SUB);
    int* deg     = (int*)(ws + OFF_DEG);
    int* part    = (int*)(ws + OFF_PART);
    int* cnt     = (int*)(ws + OFF_CNT);
    int* rowptr  = (int*)(ws + OFF_ROWPTR);
    int* elist   = (int*)(ws + OFF_ELIST);
    int* bsums   = (int*)(ws + OFF_BSUMS);
    int* boffs   = (int*)(ws + OFF_BOFFS);
    float* out   = (float*)d_out;

    hipMemsetAsync(deg, 0, (size_t)N_NODES * 4, stream);
    hipMemsetAsync(cnt, 0, (size_t)N_NODES * 4, stream);

    // weight transposes to K-major bf16 (tiny)
    transpose_cvt_kernel<<<(F_IN*HC + 255)/256, 256, 0, stream>>>(W1, Wt1, F_IN, HC);
    transpose_cvt_kernel<<<(HC*HID + 255)/256, 256, 0, stream>>>(W2, Wt2, HC, HID);

    // GEMM1: H1raw = x @ W1  (A fp32 inline-convert, B bf16 via global_load_lds)
    gemm_mfma_kernel<false><<<dim3(N_NODES/128, HC/128), 256, 0, stream>>>(
        x, Wt1, H1raw, N_NODES, HC, F_IN);
    attn1_kernel<<<N_NODES/4, 256, 0, stream>>>(H1raw, as1, ad1, asrc1, adst1);

    // CSR (dst-grouped) of original edges
    hist_kernel<<<N_EDGE/256, 256, 0, stream>>>(dst0, deg);
    scan1_kernel<<<N_NODES/256, 256, 0, stream>>>(deg, part, bsums);
    scan2_kernel<<<1, 256, 0, stream>>>(bsums, boffs, N_NODES/256);
    scan3_kernel<<<N_NODES/256, 256, 0, stream>>>(part, boffs, rowptr);
    fill_kernel<<<N_EDGE/256, 256, 0, stream>>>(src0, dst0, rowptr, cnt, elist);

    gat1_kernel<<<N_NODES, 256, 0, stream>>>(H1raw, asrc1, adst1, rowptr, elist, b1, h1b);

    // GEMM2: h2raw = h1 @ W2  (both operands bf16 via global_load_lds)
    gemm_mfma_kernel<true><<<dim3(N_NODES/128, HID/128), 256, 0, stream>>>(
        h1b, Wt2, h2raw, N_NODES, HID, HC);
    attn2_kernel<<<N_NODES/4, 256, 0, stream>>>(h2raw, as2, ad2, asrc2, adst2);

    gat2_kernel<<<N_NODES, 128, 0, stream>>>(h2raw, asrc2, adst2, rowptr, elist, b2, Wc, bc, h2, Sbuf);

    agg_kernel<<<N_GRAPH, 256, 0, stream>>>(src0, dst0, Sbuf, aggb);
    loss_kernel<<<1, 256, 0, stream>>>(aggb, out + N_GRAPH*2);

    sub_kernel<<<N_GRAPH, 128, 0, stream>>>(Sbuf, h2, subb);
    final_kernel<<<N_GRAPH, 128, 0, stream>>>(subb, Wf1, bf1, Wf2, bf2, out);

    (void)in_sizes; (void)n_in; (void)out_size; (void)ws_size;
}